// Round 5
// baseline (169.769 us; speedup 1.0000x reference)
//
#include <hip/hip_runtime.h>
#include <hip/hip_bf16.h>
#include <math.h>

// ---------------------------------------------------------------------------
// SupConLoss on MI355X.
// out = 0.5*CE(predicts,targets) + 0.5*nt_xent(Anorm, temp=0.1)
//       + 0.25*nt_xent2(Anorm, temp=0.05)
// Round 5: round-4 structure with the spill fixed.
//  - __launch_bounds__(256) ONLY (round 4's ",4" capped VGPRs at 64 and
//    spilled the 64-reg accumulator: WRITE_SIZE 4MB->100MB. Never again.)
//  - single-pass epilogue: one __expf per element (e20 = e10*e10), vmax
//    tracked instead of max(20v); A-side partials reduced over lane bits
//    0-3, B-side partials (16 regs) over lane bits 4-5.
// Exp sums unshifted (|exponent|<=20, fp32-safe); reference row-max shift
// applied exactly in merge: S_j = s2_raw * exp(-20*vmax_j).
// ---------------------------------------------------------------------------

typedef __attribute__((ext_vector_type(8))) short bf16x8;
typedef __attribute__((ext_vector_type(4))) float f32x4;

__device__ __forceinline__ float blockReduceSum(float v, float* sbuf) {
#pragma unroll
  for (int o = 32; o > 0; o >>= 1) v += __shfl_down(v, o, 64);
  int lane = threadIdx.x & 63;
  int w = threadIdx.x >> 6;
  __syncthreads();
  if (lane == 0) sbuf[w] = v;
  __syncthreads();
  return sbuf[0] + sbuf[1] + sbuf[2] + sbuf[3];
}

// --- 1. fused normalize (bf16 out) + per-row CE ----------------------------
__global__ void k_prep(const float* __restrict__ X, const float* __restrict__ P,
                       const int* __restrict__ tgt,
                       unsigned short* __restrict__ Ab,
                       float* __restrict__ ce_row, int D, int C) {
  __shared__ float sbuf[8];
  int row = blockIdx.x;
  const float* x = X + (size_t)row * D;
  unsigned short* a = Ab + (size_t)row * D;
  float ss = 0.f;
  for (int j = threadIdx.x; j < D; j += blockDim.x) {
    float v = x[j];
    ss += v * v;
  }
  ss = blockReduceSum(ss, sbuf);
  float inv = 1.0f / fmaxf(sqrtf(ss), 1e-12f);
  for (int j = threadIdx.x; j < D; j += blockDim.x) {
    union { __hip_bfloat16 h; unsigned short u; } cv;
    cv.h = __float2bfloat16(x[j] * inv);
    a[j] = cv.u;
  }
  if (threadIdx.x == 0) {
    const float* p = P + (size_t)row * C;
    float m = -INFINITY;
    for (int c = 0; c < C; ++c) m = fmaxf(m, p[c]);
    float s = 0.f;
    for (int c = 0; c < C; ++c) s += expf(p[c] - m);
    int t = tgt[row];
    ce_row[row] = -(p[t] - m - logf(s));
  }
}

// --- 2. fused symmetric GEMM + register-direct stats -----------------------
// part layout: float4 part[N][NB]; (psum, s1_raw, s2_raw, m2=20*vmax_neg).
__global__ __launch_bounds__(256) void k_gemm_fused(
    const unsigned short* __restrict__ A, const int* __restrict__ lab,
    float4* __restrict__ part, int N, int K, int NB) {
  __shared__ unsigned short Asm[128 * 32];  // 8 KB
  __shared__ unsigned short Bsm[128 * 32];  // 8 KB
  __shared__ float4 red[256];               // 4 KB
  __shared__ int labR[128];
  __shared__ int labC[128];

  // triangular decode: bid -> (by, bx), by >= bx
  int bid = blockIdx.x;
  int by = (int)((sqrtf(8.f * (float)bid + 1.f) - 1.f) * 0.5f);
  while ((by + 1) * (by + 2) / 2 <= bid) ++by;
  while (by * (by + 1) / 2 > bid) --by;
  int bx = bid - by * (by + 1) / 2;

  const int t = threadIdx.x;
  const int lane = t & 63;
  const int w = t >> 6;
  const int rowBase = by * 128;
  const int colBase = bx * 128;
  const int wr = (w >> 1) * 64;
  const int wc = (w & 1) * 64;

  if (t < 128) labR[t] = lab[rowBase + t];
  else labC[t - 128] = lab[colBase + (t - 128)];

  f32x4 acc[4][4] = {};
  const int sr = t >> 2;
  const int sc = (t & 3) * 8;

  for (int k0 = 0; k0 < K; k0 += 32) {
#pragma unroll
    for (int p = 0; p < 2; ++p) {
      const unsigned short* ga =
          A + (size_t)(rowBase + p * 64 + sr) * K + k0 + sc;
      __builtin_amdgcn_global_load_lds(
          (const __attribute__((address_space(1))) unsigned int*)ga,
          (__attribute__((address_space(3))) unsigned int*)&Asm[p * 2048 +
                                                                t * 8],
          16, 0, 0);
      const unsigned short* gb =
          A + (size_t)(colBase + p * 64 + sr) * K + k0 + sc;
      __builtin_amdgcn_global_load_lds(
          (const __attribute__((address_space(1))) unsigned int*)gb,
          (__attribute__((address_space(3))) unsigned int*)&Bsm[p * 2048 +
                                                                t * 8],
          16, 0, 0);
    }
    __syncthreads();
    bf16x8 af[4], bf[4];
#pragma unroll
    for (int mt = 0; mt < 4; ++mt)
      af[mt] = *(const bf16x8*)&Asm[(wr + mt * 16 + (lane & 15)) * 32 +
                                    (lane >> 4) * 8];
#pragma unroll
    for (int nt = 0; nt < 4; ++nt)
      bf[nt] = *(const bf16x8*)&Bsm[(wc + nt * 16 + (lane & 15)) * 32 +
                                    (lane >> 4) * 8];
#pragma unroll
    for (int mt = 0; mt < 4; ++mt)
#pragma unroll
      for (int nt = 0; nt < 4; ++nt)
        acc[mt][nt] = __builtin_amdgcn_mfma_f32_16x16x32_bf16(
            af[mt], bf[nt], acc[mt][nt], 0, 0, 0);
    __syncthreads();
  }

  // ---- epilogue: single-pass register-direct stats ------------------------
  // element: row = wr + mt*16 + (lane>>4)*4 + r ; col = wc + nt*16 + (lane&15)
  int rl[4][4], cl[4];
#pragma unroll
  for (int mt = 0; mt < 4; ++mt)
#pragma unroll
    for (int r = 0; r < 4; ++r)
      rl[mt][r] = labR[wr + mt * 16 + (lane >> 4) * 4 + r];
#pragma unroll
  for (int nt = 0; nt < 4; ++nt) cl[nt] = labC[wc + nt * 16 + (lane & 15)];
  const bool dg = (by == bx);

  float bps[4] = {}, bs1[4] = {}, bs2[4] = {};
  float bvm[4] = {-1e30f, -1e30f, -1e30f, -1e30f};

#pragma unroll
  for (int mt = 0; mt < 4; ++mt) {
#pragma unroll
    for (int r = 0; r < 4; ++r) {
      int rowL = wr + mt * 16 + (lane >> 4) * 4 + r;
      int lr = rl[mt][r];
      float ps = 0.f, s1 = 0.f, s2 = 0.f, vm = -1e30f;
#pragma unroll
      for (int nt = 0; nt < 4; ++nt) {
        float v = acc[mt][nt][r];
        int colL = wc + nt * 16 + (lane & 15);
        bool diag = dg && (rowL == colL);
        bool same = (lr == cl[nt]);
        float e10 = __expf(v * 10.f);
        float e20 = e10 * e10;
        float s1c = diag ? 1.f : e10;
        s1 += s1c;
        ps += (same && !diag) ? v : 0.f;
        s2 += same ? 0.f : e20;
        vm = same ? vm : fmaxf(vm, v);
        // B-side (only consumed when by != bx, where diag never holds)
        bs1[nt] += e10;
        bps[nt] += same ? v : 0.f;
        bs2[nt] += same ? 0.f : e20;
        bvm[nt] = same ? bvm[nt] : fmaxf(bvm[nt], v);
      }
#pragma unroll
      for (int o = 1; o < 16; o <<= 1) {
        ps += __shfl_xor(ps, o, 64);
        s1 += __shfl_xor(s1, o, 64);
        s2 += __shfl_xor(s2, o, 64);
        vm = fmaxf(vm, __shfl_xor(vm, o, 64));
      }
      // lane with (lane&15) == mt*4+r writes this row (one writer per row)
      if ((lane & 15) == mt * 4 + r)
        red[rowL * 2 + (w & 1)] = make_float4(ps, s1, s2, 20.f * vm);
    }
  }
  __syncthreads();
  if (t < 128) {
    float4 a = red[t * 2], b = red[t * 2 + 1];
    part[(size_t)(rowBase + t) * NB + bx] =
        make_float4(a.x + b.x, a.y + b.y, a.z + b.z, fmaxf(a.w, b.w));
  }

  if (by != bx) {
    __syncthreads();  // protect red reuse
#pragma unroll
    for (int nt = 0; nt < 4; ++nt) {
      float ps = bps[nt], s1 = bs1[nt], s2 = bs2[nt], vm = bvm[nt];
#pragma unroll
      for (int o = 16; o < 64; o <<= 1) {
        ps += __shfl_xor(ps, o, 64);
        s1 += __shfl_xor(s1, o, 64);
        s2 += __shfl_xor(s2, o, 64);
        vm = fmaxf(vm, __shfl_xor(vm, o, 64));
      }
      if ((lane >> 4) == 0) {
        int colL = wc + nt * 16 + (lane & 15);
        red[colL * 2 + (w >> 1)] = make_float4(ps, s1, s2, 20.f * vm);
      }
    }
    __syncthreads();
    if (t < 128) {
      float4 a = red[t * 2], b = red[t * 2 + 1];
      part[(size_t)(colBase + t) * NB + by] =
          make_float4(a.x + b.x, a.y + b.y, a.z + b.z, fmaxf(a.w, b.w));
    }
  }
}

// --- 3. merge partials per row --------------------------------------------
__global__ void k_merge(const float4* __restrict__ part,
                        float* __restrict__ psumRow,
                        float* __restrict__ logS1, float* __restrict__ Srow,
                        int N, int NB) {
  int lane = threadIdx.x & 63;
  int w = threadIdx.x >> 6;
  int row = blockIdx.x * 4 + w;
  float ps = 0.f, s1 = 0.f, s2 = 0.f, m2 = -1e30f;
  if (lane < NB) {
    float4 p = part[(size_t)row * NB + lane];
    ps = p.x; s1 = p.y; s2 = p.z; m2 = p.w;
  }
#pragma unroll
  for (int o = 16; o > 0; o >>= 1) {
    ps += __shfl_down(ps, o, 64);
    s1 += __shfl_down(s1, o, 64);
    s2 += __shfl_down(s2, o, 64);
    m2 = fmaxf(m2, __shfl_down(m2, o, 64));
  }
  if (lane == 0) {
    psumRow[row] = ps;
    logS1[row] = logf(s1);
    Srow[row] = (m2 < -1e29f) ? 0.f : s2 * expf(-m2);
  }
}

// --- 4. finalize ----------------------------------------------------------
__global__ void k_final(const float* __restrict__ ce_row,
                        const float* __restrict__ psumRow,
                        const float* __restrict__ logS1,
                        const float* __restrict__ Srow,
                        const int* __restrict__ lab, float* __restrict__ out,
                        int N, int C) {
  __shared__ float classS[32];
  __shared__ int classCnt[32];
  __shared__ float sbuf[8];
  if (threadIdx.x < 32) {
    classS[threadIdx.x] = 0.f;
    classCnt[threadIdx.x] = 0;
  }
  __syncthreads();
  float sumCe = 0.f;
  for (int i = threadIdx.x; i < N; i += blockDim.x) {
    sumCe += ce_row[i];
    int l = lab[i];
    atomicAdd(&classCnt[l], 1);
    atomicAdd(&classS[l], Srow[i]);
  }
  __syncthreads();
  float sumP1 = 0.f;
  for (int i = threadIdx.x; i < N; i += blockDim.x) {
    int l = lab[i];
    int pc = classCnt[l] - 1;
    if (pc > 0) sumP1 += psumRow[i] * 10.f / (float)pc - logS1[i];
  }
  sumCe = blockReduceSum(sumCe, sbuf);
  sumP1 = blockReduceSum(sumP1, sbuf);
  if (threadIdx.x == 0) {
    float totS = 0.f;
    for (int c = 0; c < C; ++c) totS += classS[c];
    float l2sum = 0.f;
    for (int c = 0; c < C; ++c) {
      int cnt = classCnt[c];
      if (cnt >= 2) {
        float negs = (float)(N - cnt);
        float x = (totS - classS[c]) / negs;
        l2sum += (float)cnt * logf(x + 1e-12f);
      }
    }
    float ce = sumCe / (float)N;
    float ntx1 = -sumP1 / (float)N;
    float ntx2 = l2sum / (float)N;
    out[0] = 0.5f * ce + 0.5f * ntx1 + 0.25f * ntx2;
  }
}

extern "C" void kernel_launch(void* const* d_in, const int* in_sizes, int n_in,
                              void* d_out, int out_size, void* d_ws,
                              size_t ws_size, hipStream_t stream) {
  const float* X = (const float*)d_in[0];  // cls_feats [N,D]
  const float* P = (const float*)d_in[1];  // predicts  [N,C]
  const int* tgt = (const int*)d_in[2];    // targets   [N]
  float* out = (float*)d_out;

  int N = in_sizes[2];
  int D = in_sizes[0] / N;
  int C = in_sizes[1] / N;
  int NB = N / 128;

  char* ws = (char*)d_ws;
  unsigned short* Ab = (unsigned short*)ws;          // N*D bf16
  float4* part = (float4*)(ws + (size_t)N * D * 2);  // N*NB float4
  float* ce_row = (float*)((char*)part + (size_t)N * NB * 16);
  float* psumRow = ce_row + N;
  float* logS1 = psumRow + N;
  float* Srow = logS1 + N;

  k_prep<<<N, 256, 0, stream>>>(X, P, tgt, Ab, ce_row, D, C);
  int nblk = NB * (NB + 1) / 2;
  k_gemm_fused<<<nblk, 256, 0, stream>>>(Ab, tgt, part, N, D, NB);
  k_merge<<<N / 4, 256, 0, stream>>>(part, psumRow, logS1, Srow, N, NB);
  k_final<<<1, 256, 0, stream>>>(ce_row, psumRow, logS1, Srow, tgt, out, N, C);
}

// Round 6
// 164.945 us; speedup vs baseline: 1.0292x; 1.0292x over previous
//
#include <hip/hip_runtime.h>
#include <hip/hip_bf16.h>
#include <math.h>

// ---------------------------------------------------------------------------
// SupConLoss on MI355X.
// out = 0.5*CE(predicts,targets) + 0.5*nt_xent(Anorm, temp=0.1)
//       + 0.25*nt_xent2(Anorm, temp=0.05)
// Round 6: triangular fused GEMM, fixed for occupancy + barrier drain.
//  - Two-pass register epilogue (A-side rows, then B-side cols, expf
//    recomputed) -> VGPR ~120 (round 5's fused pass hit 160 and tanked
//    occupancy to 7.5%).
//  - Single-barrier double-buffered staging: prefetch tile k+1 issued AFTER
//    the barrier publishing tile k, so the forced vmcnt(0) at the next
//    barrier overlaps load latency with ds_read+MFMA of tile k.
// Exp sums unshifted (|exponent|<=20, fp32-safe); reference row-max shift
// applied exactly in merge: S_j = s2_raw * exp(-20*vmax_j).
// ---------------------------------------------------------------------------

typedef __attribute__((ext_vector_type(8))) short bf16x8;
typedef __attribute__((ext_vector_type(4))) float f32x4;

__device__ __forceinline__ float blockReduceSum(float v, float* sbuf) {
#pragma unroll
  for (int o = 32; o > 0; o >>= 1) v += __shfl_down(v, o, 64);
  int lane = threadIdx.x & 63;
  int w = threadIdx.x >> 6;
  __syncthreads();
  if (lane == 0) sbuf[w] = v;
  __syncthreads();
  return sbuf[0] + sbuf[1] + sbuf[2] + sbuf[3];
}

// --- 1. fused normalize (bf16 out) + per-row CE ----------------------------
__global__ void k_prep(const float* __restrict__ X, const float* __restrict__ P,
                       const int* __restrict__ tgt,
                       unsigned short* __restrict__ Ab,
                       float* __restrict__ ce_row, int D, int C) {
  __shared__ float sbuf[8];
  int row = blockIdx.x;
  const float* x = X + (size_t)row * D;
  unsigned short* a = Ab + (size_t)row * D;
  float ss = 0.f;
  for (int j = threadIdx.x; j < D; j += blockDim.x) {
    float v = x[j];
    ss += v * v;
  }
  ss = blockReduceSum(ss, sbuf);
  float inv = 1.0f / fmaxf(sqrtf(ss), 1e-12f);
  for (int j = threadIdx.x; j < D; j += blockDim.x) {
    union { __hip_bfloat16 h; unsigned short u; } cv;
    cv.h = __float2bfloat16(x[j] * inv);
    a[j] = cv.u;
  }
  if (threadIdx.x == 0) {
    const float* p = P + (size_t)row * C;
    float m = -INFINITY;
    for (int c = 0; c < C; ++c) m = fmaxf(m, p[c]);
    float s = 0.f;
    for (int c = 0; c < C; ++c) s += expf(p[c] - m);
    int t = tgt[row];
    ce_row[row] = -(p[t] - m - logf(s));
  }
}

// --- 2. fused symmetric GEMM + two-pass register stats ---------------------
// part layout: float4 part[N][NB]; (psum, s1_raw, s2_raw, m2=20*vmax_neg).
__global__ __launch_bounds__(256) void k_gemm_fused(
    const unsigned short* __restrict__ A, const int* __restrict__ lab,
    float4* __restrict__ part, int N, int K, int NB) {
  __shared__ unsigned short Asm[2][128 * 32];  // 2 x 8 KB
  __shared__ unsigned short Bsm[2][128 * 32];  // 2 x 8 KB
  __shared__ float4 red[256];                  // 4 KB
  __shared__ int labR[128];
  __shared__ int labC[128];

  // triangular decode: bid -> (by, bx), by >= bx
  int bid = blockIdx.x;
  int by = (int)((sqrtf(8.f * (float)bid + 1.f) - 1.f) * 0.5f);
  while ((by + 1) * (by + 2) / 2 <= bid) ++by;
  while (by * (by + 1) / 2 > bid) --by;
  int bx = bid - by * (by + 1) / 2;

  const int t = threadIdx.x;
  const int lane = t & 63;
  const int w = t >> 6;
  const int rowBase = by * 128;
  const int colBase = bx * 128;
  const int wr = (w >> 1) * 64;
  const int wc = (w & 1) * 64;

  const int sr = t >> 2;
  const int sc = (t & 3) * 8;
  const unsigned short* gA = A + (size_t)(rowBase + sr) * K + sc;
  const unsigned short* gB = A + (size_t)(colBase + sr) * K + sc;

  // prologue: stage k0=0 into buffer 0
#pragma unroll
  for (int p = 0; p < 2; ++p) {
    __builtin_amdgcn_global_load_lds(
        (const __attribute__((address_space(1))) unsigned int*)(gA +
                                                                (size_t)p * 64 * K),
        (__attribute__((address_space(3))) unsigned int*)&Asm[0][p * 2048 + t * 8],
        16, 0, 0);
    __builtin_amdgcn_global_load_lds(
        (const __attribute__((address_space(1))) unsigned int*)(gB +
                                                                (size_t)p * 64 * K),
        (__attribute__((address_space(3))) unsigned int*)&Bsm[0][p * 2048 + t * 8],
        16, 0, 0);
  }

  if (t < 128) labR[t] = lab[rowBase + t];
  else labC[t - 128] = lab[colBase + (t - 128)];

  f32x4 acc[4][4] = {};
  const int KB = K / 32;
  for (int kb = 0; kb < KB; ++kb) {
    __syncthreads();  // publishes buffer kb&1 (drains its loads)
    int cur = kb & 1;
    if (kb + 1 < KB) {
      int nxt = cur ^ 1;
      int koff = (kb + 1) * 32;
#pragma unroll
      for (int p = 0; p < 2; ++p) {
        __builtin_amdgcn_global_load_lds(
            (const __attribute__((address_space(1))) unsigned int*)(gA +
                (size_t)p * 64 * K + koff),
            (__attribute__((address_space(3))) unsigned int*)&Asm[nxt][p * 2048 + t * 8],
            16, 0, 0);
        __builtin_amdgcn_global_load_lds(
            (const __attribute__((address_space(1))) unsigned int*)(gB +
                (size_t)p * 64 * K + koff),
            (__attribute__((address_space(3))) unsigned int*)&Bsm[nxt][p * 2048 + t * 8],
            16, 0, 0);
      }
    }
    bf16x8 af[4], bf[4];
#pragma unroll
    for (int mt = 0; mt < 4; ++mt)
      af[mt] = *(const bf16x8*)&Asm[cur][(wr + mt * 16 + (lane & 15)) * 32 +
                                         (lane >> 4) * 8];
#pragma unroll
    for (int nt = 0; nt < 4; ++nt)
      bf[nt] = *(const bf16x8*)&Bsm[cur][(wc + nt * 16 + (lane & 15)) * 32 +
                                         (lane >> 4) * 8];
#pragma unroll
    for (int mt = 0; mt < 4; ++mt)
#pragma unroll
      for (int nt = 0; nt < 4; ++nt)
        acc[mt][nt] = __builtin_amdgcn_mfma_f32_16x16x32_bf16(
            af[mt], bf[nt], acc[mt][nt], 0, 0, 0);
  }

  // ---- epilogue ----------------------------------------------------------
  // element: row = wr + mt*16 + (lane>>4)*4 + r ; col = wc + nt*16 + (lane&15)
  int rl[4][4], cl[4];
#pragma unroll
  for (int mt = 0; mt < 4; ++mt)
#pragma unroll
    for (int r = 0; r < 4; ++r)
      rl[mt][r] = labR[wr + mt * 16 + (lane >> 4) * 4 + r];
#pragma unroll
  for (int nt = 0; nt < 4; ++nt) cl[nt] = labC[wc + nt * 16 + (lane & 15)];
  const bool dg = (by == bx);

  // Pass A: per-row stats (reduce over lane bits 0-3).
#pragma unroll
  for (int mt = 0; mt < 4; ++mt) {
#pragma unroll
    for (int r = 0; r < 4; ++r) {
      int rowL = wr + mt * 16 + (lane >> 4) * 4 + r;
      int lr = rl[mt][r];
      float ps = 0.f, s1 = 0.f, s2 = 0.f, vm = -1e30f;
#pragma unroll
      for (int nt = 0; nt < 4; ++nt) {
        float v = acc[mt][nt][r];
        int colL = wc + nt * 16 + (lane & 15);
        bool diag = dg && (rowL == colL);
        bool same = (lr == cl[nt]);
        float e10 = __expf(v * 10.f);
        s1 += diag ? 1.f : e10;
        ps += (same && !diag) ? v : 0.f;
        s2 += same ? 0.f : e10 * e10;
        vm = same ? vm : fmaxf(vm, v);
      }
#pragma unroll
      for (int o = 1; o < 16; o <<= 1) {
        ps += __shfl_xor(ps, o, 64);
        s1 += __shfl_xor(s1, o, 64);
        s2 += __shfl_xor(s2, o, 64);
        vm = fmaxf(vm, __shfl_xor(vm, o, 64));
      }
      if ((lane & 15) == mt * 4 + r)
        red[rowL * 2 + (w & 1)] = make_float4(ps, s1, s2, 20.f * vm);
    }
  }
  __syncthreads();
  if (t < 128) {
    float4 a = red[t * 2], b = red[t * 2 + 1];
    part[(size_t)(rowBase + t) * NB + bx] =
        make_float4(a.x + b.x, a.y + b.y, a.z + b.z, fmaxf(a.w, b.w));
  }

  // Pass B (off-diagonal only): per-col stats (reduce over lane bits 4-5).
  if (by != bx) {
    __syncthreads();  // protect red reuse
#pragma unroll
    for (int nt = 0; nt < 4; ++nt) {
      int colL = wc + nt * 16 + (lane & 15);
      int lc = cl[nt];
      float ps = 0.f, s1 = 0.f, s2 = 0.f, vm = -1e30f;
#pragma unroll
      for (int mt = 0; mt < 4; ++mt)
#pragma unroll
        for (int r = 0; r < 4; ++r) {
          float v = acc[mt][nt][r];
          bool same = (rl[mt][r] == lc);
          float e10 = __expf(v * 10.f);
          s1 += e10;
          ps += same ? v : 0.f;
          s2 += same ? 0.f : e10 * e10;
          vm = same ? vm : fmaxf(vm, v);
        }
#pragma unroll
      for (int o = 16; o < 64; o <<= 1) {
        ps += __shfl_xor(ps, o, 64);
        s1 += __shfl_xor(s1, o, 64);
        s2 += __shfl_xor(s2, o, 64);
        vm = fmaxf(vm, __shfl_xor(vm, o, 64));
      }
      if ((lane >> 4) == 0)
        red[colL * 2 + (w >> 1)] = make_float4(ps, s1, s2, 20.f * vm);
    }
    __syncthreads();
    if (t < 128) {
      float4 a = red[t * 2], b = red[t * 2 + 1];
      part[(size_t)(colBase + t) * NB + by] =
          make_float4(a.x + b.x, a.y + b.y, a.z + b.z, fmaxf(a.w, b.w));
    }
  }
}

// --- 3. merge partials per row --------------------------------------------
__global__ void k_merge(const float4* __restrict__ part,
                        float* __restrict__ psumRow,
                        float* __restrict__ logS1, float* __restrict__ Srow,
                        int N, int NB) {
  int lane = threadIdx.x & 63;
  int w = threadIdx.x >> 6;
  int row = blockIdx.x * 4 + w;
  float ps = 0.f, s1 = 0.f, s2 = 0.f, m2 = -1e30f;
  if (lane < NB) {
    float4 p = part[(size_t)row * NB + lane];
    ps = p.x; s1 = p.y; s2 = p.z; m2 = p.w;
  }
#pragma unroll
  for (int o = 16; o > 0; o >>= 1) {
    ps += __shfl_down(ps, o, 64);
    s1 += __shfl_down(s1, o, 64);
    s2 += __shfl_down(s2, o, 64);
    m2 = fmaxf(m2, __shfl_down(m2, o, 64));
  }
  if (lane == 0) {
    psumRow[row] = ps;
    logS1[row] = logf(s1);
    Srow[row] = (m2 < -1e29f) ? 0.f : s2 * expf(-m2);
  }
}

// --- 4. finalize ----------------------------------------------------------
__global__ void k_final(const float* __restrict__ ce_row,
                        const float* __restrict__ psumRow,
                        const float* __restrict__ logS1,
                        const float* __restrict__ Srow,
                        const int* __restrict__ lab, float* __restrict__ out,
                        int N, int C) {
  __shared__ float classS[32];
  __shared__ int classCnt[32];
  __shared__ float sbuf[8];
  if (threadIdx.x < 32) {
    classS[threadIdx.x] = 0.f;
    classCnt[threadIdx.x] = 0;
  }
  __syncthreads();
  float sumCe = 0.f;
  for (int i = threadIdx.x; i < N; i += blockDim.x) {
    sumCe += ce_row[i];
    int l = lab[i];
    atomicAdd(&classCnt[l], 1);
    atomicAdd(&classS[l], Srow[i]);
  }
  __syncthreads();
  float sumP1 = 0.f;
  for (int i = threadIdx.x; i < N; i += blockDim.x) {
    int l = lab[i];
    int pc = classCnt[l] - 1;
    if (pc > 0) sumP1 += psumRow[i] * 10.f / (float)pc - logS1[i];
  }
  sumCe = blockReduceSum(sumCe, sbuf);
  sumP1 = blockReduceSum(sumP1, sbuf);
  if (threadIdx.x == 0) {
    float totS = 0.f;
    for (int c = 0; c < C; ++c) totS += classS[c];
    float l2sum = 0.f;
    for (int c = 0; c < C; ++c) {
      int cnt = classCnt[c];
      if (cnt >= 2) {
        float negs = (float)(N - cnt);
        float x = (totS - classS[c]) / negs;
        l2sum += (float)cnt * logf(x + 1e-12f);
      }
    }
    float ce = sumCe / (float)N;
    float ntx1 = -sumP1 / (float)N;
    float ntx2 = l2sum / (float)N;
    out[0] = 0.5f * ce + 0.5f * ntx1 + 0.25f * ntx2;
  }
}

extern "C" void kernel_launch(void* const* d_in, const int* in_sizes, int n_in,
                              void* d_out, int out_size, void* d_ws,
                              size_t ws_size, hipStream_t stream) {
  const float* X = (const float*)d_in[0];  // cls_feats [N,D]
  const float* P = (const float*)d_in[1];  // predicts  [N,C]
  const int* tgt = (const int*)d_in[2];    // targets   [N]
  float* out = (float*)d_out;

  int N = in_sizes[2];
  int D = in_sizes[0] / N;
  int C = in_sizes[1] / N;
  int NB = N / 128;

  char* ws = (char*)d_ws;
  unsigned short* Ab = (unsigned short*)ws;          // N*D bf16
  float4* part = (float4*)(ws + (size_t)N * D * 2);  // N*NB float4
  float* ce_row = (float*)((char*)part + (size_t)N * NB * 16);
  float* psumRow = ce_row + N;
  float* logS1 = psumRow + N;
  float* Srow = logS1 + N;

  k_prep<<<N, 256, 0, stream>>>(X, P, tgt, Ab, ce_row, D, C);
  int nblk = NB * (NB + 1) / 2;
  k_gemm_fused<<<nblk, 256, 0, stream>>>(Ab, tgt, part, N, D, NB);
  k_merge<<<N / 4, 256, 0, stream>>>(part, psumRow, logS1, Srow, N, NB);
  k_final<<<1, 256, 0, stream>>>(ce_row, psumRow, logS1, Srow, tgt, out, N, C);
}

// Round 7
// 148.337 us; speedup vs baseline: 1.1445x; 1.1120x over previous
//
#include <hip/hip_runtime.h>
#include <hip/hip_bf16.h>
#include <math.h>

// ---------------------------------------------------------------------------
// SupConLoss on MI355X.
// out = 0.5*CE(predicts,targets) + 0.5*nt_xent(Anorm, temp=0.1)
//       + 0.25*nt_xent2(Anorm, temp=0.05)
// Round 7: single-wave 64x64 triangular tiles.
//  - 2080 blocks of ONE wave each (8.1 blocks/CU) -> grid no longer caps
//    occupancy (round 6: 528 blocks = 2.06/CU was the limiter).
//  - No __syncthreads at all: LDS producer/consumer are the same wave, so
//    the vmcnt(0)+barrier drain is structurally gone; dbuf prefetch rides
//    on compiler s_waitcnt only.
//  - Fused single-pass epilogue (A-side rows + B-side cols accumulated
//    together); at 2 waves/SIMD grid-bound occupancy, the +16 VGPRs are free.
// Exp sums unshifted (|exponent|<=20, fp32-safe); reference row-max shift
// applied exactly in merge: S_j = s2_raw * exp(-20*vmax_j).
// ---------------------------------------------------------------------------

typedef __attribute__((ext_vector_type(8))) short bf16x8;
typedef __attribute__((ext_vector_type(4))) float f32x4;

__device__ __forceinline__ float blockReduceSum(float v, float* sbuf) {
#pragma unroll
  for (int o = 32; o > 0; o >>= 1) v += __shfl_down(v, o, 64);
  int lane = threadIdx.x & 63;
  int w = threadIdx.x >> 6;
  __syncthreads();
  if (lane == 0) sbuf[w] = v;
  __syncthreads();
  return sbuf[0] + sbuf[1] + sbuf[2] + sbuf[3];
}

// --- 1. fused normalize (bf16 out) + per-row CE ----------------------------
__global__ void k_prep(const float* __restrict__ X, const float* __restrict__ P,
                       const int* __restrict__ tgt,
                       unsigned short* __restrict__ Ab,
                       float* __restrict__ ce_row, int D, int C) {
  __shared__ float sbuf[8];
  int row = blockIdx.x;
  const float* x = X + (size_t)row * D;
  unsigned short* a = Ab + (size_t)row * D;
  float ss = 0.f;
  for (int j = threadIdx.x; j < D; j += blockDim.x) {
    float v = x[j];
    ss += v * v;
  }
  ss = blockReduceSum(ss, sbuf);
  float inv = 1.0f / fmaxf(sqrtf(ss), 1e-12f);
  for (int j = threadIdx.x; j < D; j += blockDim.x) {
    union { __hip_bfloat16 h; unsigned short u; } cv;
    cv.h = __float2bfloat16(x[j] * inv);
    a[j] = cv.u;
  }
  if (threadIdx.x == 0) {
    const float* p = P + (size_t)row * C;
    float m = -INFINITY;
    for (int c = 0; c < C; ++c) m = fmaxf(m, p[c]);
    float s = 0.f;
    for (int c = 0; c < C; ++c) s += expf(p[c] - m);
    int t = tgt[row];
    ce_row[row] = -(p[t] - m - logf(s));
  }
}

// --- 2. single-wave 64x64 fused symmetric GEMM + stats ---------------------
// part layout: float4 part[N][NB]; (psum, s1_raw, s2_raw, m2=20*vmax_neg).
__global__ __launch_bounds__(64) void k_gemm_fused(
    const unsigned short* __restrict__ A, const int* __restrict__ lab,
    float4* __restrict__ part, int N, int K, int NB) {
  __shared__ unsigned short Asm[2][64 * 32];  // 2 x 4 KB
  __shared__ unsigned short Bsm[2][64 * 32];  // 2 x 4 KB
  __shared__ int labR[64];
  __shared__ int labC[64];

  // triangular decode: bid -> (by, bx), by >= bx
  int bid = blockIdx.x;
  int by = (int)((sqrtf(8.f * (float)bid + 1.f) - 1.f) * 0.5f);
  while ((by + 1) * (by + 2) / 2 <= bid) ++by;
  while (by * (by + 1) / 2 > bid) --by;
  int bx = bid - by * (by + 1) / 2;

  const int t = threadIdx.x;  // == lane (single wave)
  const int rowBase = by * 64;
  const int colBase = bx * 64;

  const int sr = t >> 2;       // 0..15
  const int sc = (t & 3) * 8;  // 0,8,16,24
  const unsigned short* gA = A + (size_t)(rowBase + sr) * K + sc;
  const unsigned short* gB = A + (size_t)(colBase + sr) * K + sc;

  // prologue: stage k0=0 into buffer 0 (4 insts per strip; rows p*16+sr)
#pragma unroll
  for (int p = 0; p < 4; ++p) {
    __builtin_amdgcn_global_load_lds(
        (const __attribute__((address_space(1))) unsigned int*)(gA +
            (size_t)p * 16 * K),
        (__attribute__((address_space(3))) unsigned int*)&Asm[0][p * 512 + t * 8],
        16, 0, 0);
    __builtin_amdgcn_global_load_lds(
        (const __attribute__((address_space(1))) unsigned int*)(gB +
            (size_t)p * 16 * K),
        (__attribute__((address_space(3))) unsigned int*)&Bsm[0][p * 512 + t * 8],
        16, 0, 0);
  }
  labR[t] = lab[rowBase + t];
  labC[t] = lab[colBase + t];

  f32x4 acc[4][4] = {};
  const int KB = K / 32;
  for (int kb = 0; kb < KB; ++kb) {
    int cur = kb & 1;
    if (kb + 1 < KB) {
      int nxt = cur ^ 1;
      int koff = (kb + 1) * 32;
#pragma unroll
      for (int p = 0; p < 4; ++p) {
        __builtin_amdgcn_global_load_lds(
            (const __attribute__((address_space(1))) unsigned int*)(gA +
                (size_t)p * 16 * K + koff),
            (__attribute__((address_space(3))) unsigned int*)&Asm[nxt][p * 512 + t * 8],
            16, 0, 0);
        __builtin_amdgcn_global_load_lds(
            (const __attribute__((address_space(1))) unsigned int*)(gB +
                (size_t)p * 16 * K + koff),
            (__attribute__((address_space(3))) unsigned int*)&Bsm[nxt][p * 512 + t * 8],
            16, 0, 0);
      }
    }
    bf16x8 af[4], bf[4];
#pragma unroll
    for (int mt = 0; mt < 4; ++mt)
      af[mt] = *(const bf16x8*)&Asm[cur][(mt * 16 + (t & 15)) * 32 +
                                         (t >> 4) * 8];
#pragma unroll
    for (int nt = 0; nt < 4; ++nt)
      bf[nt] = *(const bf16x8*)&Bsm[cur][(nt * 16 + (t & 15)) * 32 +
                                         (t >> 4) * 8];
#pragma unroll
    for (int mt = 0; mt < 4; ++mt)
#pragma unroll
      for (int nt = 0; nt < 4; ++nt)
        acc[mt][nt] = __builtin_amdgcn_mfma_f32_16x16x32_bf16(
            af[mt], bf[nt], acc[mt][nt], 0, 0, 0);
  }

  // ---- fused single-pass epilogue ----------------------------------------
  // element: row = mt*16 + (t>>4)*4 + r ; col = nt*16 + (t&15)
  int cl[4];
#pragma unroll
  for (int nt = 0; nt < 4; ++nt) cl[nt] = labC[nt * 16 + (t & 15)];
  const bool dg = (by == bx);

  float bps[4] = {}, bs1[4] = {}, bs2[4] = {};
  float bvm[4] = {-1e30f, -1e30f, -1e30f, -1e30f};

#pragma unroll
  for (int mt = 0; mt < 4; ++mt) {
#pragma unroll
    for (int r = 0; r < 4; ++r) {
      int rowL = mt * 16 + (t >> 4) * 4 + r;
      int lr = labR[rowL];
      float ps = 0.f, s1 = 0.f, s2 = 0.f, vm = -1e30f;
#pragma unroll
      for (int nt = 0; nt < 4; ++nt) {
        float v = acc[mt][nt][r];
        int colL = nt * 16 + (t & 15);
        bool diag = dg && (rowL == colL);
        bool same = (lr == cl[nt]);
        float e10 = __expf(v * 10.f);
        float e20 = e10 * e10;
        s1 += diag ? 1.f : e10;
        ps += (same && !diag) ? v : 0.f;
        s2 += same ? 0.f : e20;
        vm = same ? vm : fmaxf(vm, v);
        if (!dg) {  // B-side accumulation (consumed only off-diagonal)
          bs1[nt] += e10;
          bps[nt] += same ? v : 0.f;
          bs2[nt] += same ? 0.f : e20;
          bvm[nt] = same ? bvm[nt] : fmaxf(bvm[nt], v);
        }
      }
#pragma unroll
      for (int o = 1; o < 16; o <<= 1) {
        ps += __shfl_xor(ps, o, 64);
        s1 += __shfl_xor(s1, o, 64);
        s2 += __shfl_xor(s2, o, 64);
        vm = fmaxf(vm, __shfl_xor(vm, o, 64));
      }
      if ((t & 15) == 0)
        part[(size_t)(rowBase + rowL) * NB + bx] =
            make_float4(ps, s1, s2, 20.f * vm);
    }
  }

  if (!dg) {
#pragma unroll
    for (int nt = 0; nt < 4; ++nt) {
      float ps = bps[nt], s1 = bs1[nt], s2 = bs2[nt], vm = bvm[nt];
#pragma unroll
      for (int o = 16; o < 64; o <<= 1) {
        ps += __shfl_xor(ps, o, 64);
        s1 += __shfl_xor(s1, o, 64);
        s2 += __shfl_xor(s2, o, 64);
        vm = fmaxf(vm, __shfl_xor(vm, o, 64));
      }
      if ((t >> 4) == 0)
        part[(size_t)(colBase + nt * 16 + (t & 15)) * NB + by] =
            make_float4(ps, s1, s2, 20.f * vm);
    }
  }
}

// --- 3. merge partials per row (64 colblocks -> full-wave reduce) ----------
__global__ void k_merge(const float4* __restrict__ part,
                        float* __restrict__ psumRow,
                        float* __restrict__ logS1, float* __restrict__ Srow,
                        int N, int NB) {
  int lane = threadIdx.x & 63;
  int w = threadIdx.x >> 6;
  int row = blockIdx.x * 4 + w;
  float ps = 0.f, s1 = 0.f, s2 = 0.f, m2 = -1e30f;
  if (lane < NB) {
    float4 p = part[(size_t)row * NB + lane];
    ps = p.x; s1 = p.y; s2 = p.z; m2 = p.w;
  }
#pragma unroll
  for (int o = 32; o > 0; o >>= 1) {
    ps += __shfl_down(ps, o, 64);
    s1 += __shfl_down(s1, o, 64);
    s2 += __shfl_down(s2, o, 64);
    m2 = fmaxf(m2, __shfl_down(m2, o, 64));
  }
  if (lane == 0) {
    psumRow[row] = ps;
    logS1[row] = logf(s1);
    Srow[row] = (m2 < -1e29f) ? 0.f : s2 * expf(-m2);
  }
}

// --- 4. finalize ----------------------------------------------------------
__global__ void k_final(const float* __restrict__ ce_row,
                        const float* __restrict__ psumRow,
                        const float* __restrict__ logS1,
                        const float* __restrict__ Srow,
                        const int* __restrict__ lab, float* __restrict__ out,
                        int N, int C) {
  __shared__ float classS[32];
  __shared__ int classCnt[32];
  __shared__ float sbuf[8];
  if (threadIdx.x < 32) {
    classS[threadIdx.x] = 0.f;
    classCnt[threadIdx.x] = 0;
  }
  __syncthreads();
  float sumCe = 0.f;
  for (int i = threadIdx.x; i < N; i += blockDim.x) {
    sumCe += ce_row[i];
    int l = lab[i];
    atomicAdd(&classCnt[l], 1);
    atomicAdd(&classS[l], Srow[i]);
  }
  __syncthreads();
  float sumP1 = 0.f;
  for (int i = threadIdx.x; i < N; i += blockDim.x) {
    int l = lab[i];
    int pc = classCnt[l] - 1;
    if (pc > 0) sumP1 += psumRow[i] * 10.f / (float)pc - logS1[i];
  }
  sumCe = blockReduceSum(sumCe, sbuf);
  sumP1 = blockReduceSum(sumP1, sbuf);
  if (threadIdx.x == 0) {
    float totS = 0.f;
    for (int c = 0; c < C; ++c) totS += classS[c];
    float l2sum = 0.f;
    for (int c = 0; c < C; ++c) {
      int cnt = classCnt[c];
      if (cnt >= 2) {
        float negs = (float)(N - cnt);
        float x = (totS - classS[c]) / negs;
        l2sum += (float)cnt * logf(x + 1e-12f);
      }
    }
    float ce = sumCe / (float)N;
    float ntx1 = -sumP1 / (float)N;
    float ntx2 = l2sum / (float)N;
    out[0] = 0.5f * ce + 0.5f * ntx1 + 0.25f * ntx2;
  }
}

extern "C" void kernel_launch(void* const* d_in, const int* in_sizes, int n_in,
                              void* d_out, int out_size, void* d_ws,
                              size_t ws_size, hipStream_t stream) {
  const float* X = (const float*)d_in[0];  // cls_feats [N,D]
  const float* P = (const float*)d_in[1];  // predicts  [N,C]
  const int* tgt = (const int*)d_in[2];    // targets   [N]
  float* out = (float*)d_out;

  int N = in_sizes[2];
  int D = in_sizes[0] / N;
  int C = in_sizes[1] / N;
  int NB = N / 64;

  char* ws = (char*)d_ws;
  unsigned short* Ab = (unsigned short*)ws;          // N*D bf16
  float4* part = (float4*)(ws + (size_t)N * D * 2);  // N*NB float4
  float* ce_row = (float*)((char*)part + (size_t)N * NB * 16);
  float* psumRow = ce_row + N;
  float* logS1 = psumRow + N;
  float* Srow = logS1 + N;

  k_prep<<<N, 256, 0, stream>>>(X, P, tgt, Ab, ce_row, D, C);
  int nblk = NB * (NB + 1) / 2;
  k_gemm_fused<<<nblk, 64, 0, stream>>>(Ab, tgt, part, N, D, NB);
  k_merge<<<N / 4, 256, 0, stream>>>(part, psumRow, logS1, Srow, N, NB);
  k_final<<<1, 256, 0, stream>>>(ce_row, psumRow, logS1, Srow, tgt, out, N, C);
}

// Round 8
// 145.861 us; speedup vs baseline: 1.1639x; 1.0170x over previous
//
#include <hip/hip_runtime.h>
#include <hip/hip_bf16.h>
#include <math.h>

// ---------------------------------------------------------------------------
// SupConLoss on MI355X.
// out = 0.5*CE(predicts,targets) + 0.5*nt_xent(Anorm, temp=0.1)
//       + 0.25*nt_xent2(Anorm, temp=0.05)
// Round 8: round-7 single-wave 64x64 triangular tiles + TRIPLE-buffered
// staging (prefetch depth 2). Round 7's dbuf gave only ~1-iter lead between
// global_load_lds issue and the consuming ds_read -> per-iter L2-latency
// stall (75% idle). Order per iter: ds_read(cur) -> prefetch(kb+2) -> MFMA,
// so even a conservative vmcnt keeps >=1-iter lead; best case 2-iter.
// LDS 24.5 KB -> 6 waves/CU (vs 9), accepted trade for stall removal.
// Exp sums unshifted (|exponent|<=20, fp32-safe); reference row-max shift
// applied exactly in merge: S_j = s2_raw * exp(-20*vmax_j).
// ---------------------------------------------------------------------------

typedef __attribute__((ext_vector_type(8))) short bf16x8;
typedef __attribute__((ext_vector_type(4))) float f32x4;

__device__ __forceinline__ float blockReduceSum(float v, float* sbuf) {
#pragma unroll
  for (int o = 32; o > 0; o >>= 1) v += __shfl_down(v, o, 64);
  int lane = threadIdx.x & 63;
  int w = threadIdx.x >> 6;
  __syncthreads();
  if (lane == 0) sbuf[w] = v;
  __syncthreads();
  return sbuf[0] + sbuf[1] + sbuf[2] + sbuf[3];
}

// --- 1. fused normalize (bf16 out) + per-row CE ----------------------------
__global__ void k_prep(const float* __restrict__ X, const float* __restrict__ P,
                       const int* __restrict__ tgt,
                       unsigned short* __restrict__ Ab,
                       float* __restrict__ ce_row, int D, int C) {
  __shared__ float sbuf[8];
  int row = blockIdx.x;
  const float* x = X + (size_t)row * D;
  unsigned short* a = Ab + (size_t)row * D;
  float ss = 0.f;
  for (int j = threadIdx.x; j < D; j += blockDim.x) {
    float v = x[j];
    ss += v * v;
  }
  ss = blockReduceSum(ss, sbuf);
  float inv = 1.0f / fmaxf(sqrtf(ss), 1e-12f);
  for (int j = threadIdx.x; j < D; j += blockDim.x) {
    union { __hip_bfloat16 h; unsigned short u; } cv;
    cv.h = __float2bfloat16(x[j] * inv);
    a[j] = cv.u;
  }
  if (threadIdx.x == 0) {
    const float* p = P + (size_t)row * C;
    float m = -INFINITY;
    for (int c = 0; c < C; ++c) m = fmaxf(m, p[c]);
    float s = 0.f;
    for (int c = 0; c < C; ++c) s += expf(p[c] - m);
    int t = tgt[row];
    ce_row[row] = -(p[t] - m - logf(s));
  }
}

// --- 2. single-wave 64x64 fused symmetric GEMM + stats, 3-buffer -----------
// part layout: float4 part[N][NB]; (psum, s1_raw, s2_raw, m2=20*vmax_neg).
__global__ __launch_bounds__(64) void k_gemm_fused(
    const unsigned short* __restrict__ A, const int* __restrict__ lab,
    float4* __restrict__ part, int N, int K, int NB) {
  __shared__ unsigned short Asm[3][64 * 32];  // 3 x 4 KB
  __shared__ unsigned short Bsm[3][64 * 32];  // 3 x 4 KB
  __shared__ int labR[64];
  __shared__ int labC[64];

  // triangular decode: bid -> (by, bx), by >= bx
  int bid = blockIdx.x;
  int by = (int)((sqrtf(8.f * (float)bid + 1.f) - 1.f) * 0.5f);
  while ((by + 1) * (by + 2) / 2 <= bid) ++by;
  while (by * (by + 1) / 2 > bid) --by;
  int bx = bid - by * (by + 1) / 2;

  const int t = threadIdx.x;  // == lane (single wave)
  const int rowBase = by * 64;
  const int colBase = bx * 64;

  labR[t] = lab[rowBase + t];
  labC[t] = lab[colBase + t];

  const int sr = t >> 2;       // 0..15
  const int sc = (t & 3) * 8;  // 0,8,16,24
  const unsigned short* gA = A + (size_t)(rowBase + sr) * K + sc;
  const unsigned short* gB = A + (size_t)(colBase + sr) * K + sc;

  // prologue: stage kb=0 -> buf0, kb=1 -> buf1
#pragma unroll
  for (int b = 0; b < 2; ++b) {
#pragma unroll
    for (int p = 0; p < 4; ++p) {
      __builtin_amdgcn_global_load_lds(
          (const __attribute__((address_space(1))) unsigned int*)(gA +
              (size_t)p * 16 * K + b * 32),
          (__attribute__((address_space(3))) unsigned int*)&Asm[b][p * 512 + t * 8],
          16, 0, 0);
      __builtin_amdgcn_global_load_lds(
          (const __attribute__((address_space(1))) unsigned int*)(gB +
              (size_t)p * 16 * K + b * 32),
          (__attribute__((address_space(3))) unsigned int*)&Bsm[b][p * 512 + t * 8],
          16, 0, 0);
    }
  }

  f32x4 acc[4][4] = {};
  const int KB = K / 32;
  int cur = 0;
  for (int kb = 0; kb < KB; ++kb) {
    // (1) consume buffer cur (loads issued 2 iterations ago)
    bf16x8 af[4], bf[4];
#pragma unroll
    for (int mt = 0; mt < 4; ++mt)
      af[mt] = *(const bf16x8*)&Asm[cur][(mt * 16 + (t & 15)) * 32 +
                                         (t >> 4) * 8];
#pragma unroll
    for (int nt = 0; nt < 4; ++nt)
      bf[nt] = *(const bf16x8*)&Bsm[cur][(nt * 16 + (t & 15)) * 32 +
                                         (t >> 4) * 8];
    // (2) issue prefetch for kb+2 into the buffer being vacated
    if (kb + 2 < KB) {
      int nxt = cur + 2;
      if (nxt >= 3) nxt -= 3;
      int koff = (kb + 2) * 32;
#pragma unroll
      for (int p = 0; p < 4; ++p) {
        __builtin_amdgcn_global_load_lds(
            (const __attribute__((address_space(1))) unsigned int*)(gA +
                (size_t)p * 16 * K + koff),
            (__attribute__((address_space(3))) unsigned int*)&Asm[nxt][p * 512 + t * 8],
            16, 0, 0);
        __builtin_amdgcn_global_load_lds(
            (const __attribute__((address_space(1))) unsigned int*)(gB +
                (size_t)p * 16 * K + koff),
            (__attribute__((address_space(3))) unsigned int*)&Bsm[nxt][p * 512 + t * 8],
            16, 0, 0);
      }
    }
    // (3) MFMA on cur
#pragma unroll
    for (int mt = 0; mt < 4; ++mt)
#pragma unroll
      for (int nt = 0; nt < 4; ++nt)
        acc[mt][nt] = __builtin_amdgcn_mfma_f32_16x16x32_bf16(
            af[mt], bf[nt], acc[mt][nt], 0, 0, 0);
    cur = (cur == 2) ? 0 : cur + 1;
  }

  // ---- fused single-pass epilogue ----------------------------------------
  // element: row = mt*16 + (t>>4)*4 + r ; col = nt*16 + (t&15)
  int cl[4];
#pragma unroll
  for (int nt = 0; nt < 4; ++nt) cl[nt] = labC[nt * 16 + (t & 15)];
  const bool dg = (by == bx);

  float bps[4] = {}, bs1[4] = {}, bs2[4] = {};
  float bvm[4] = {-1e30f, -1e30f, -1e30f, -1e30f};

#pragma unroll
  for (int mt = 0; mt < 4; ++mt) {
#pragma unroll
    for (int r = 0; r < 4; ++r) {
      int rowL = mt * 16 + (t >> 4) * 4 + r;
      int lr = labR[rowL];
      float ps = 0.f, s1 = 0.f, s2 = 0.f, vm = -1e30f;
#pragma unroll
      for (int nt = 0; nt < 4; ++nt) {
        float v = acc[mt][nt][r];
        int colL = nt * 16 + (t & 15);
        bool diag = dg && (rowL == colL);
        bool same = (lr == cl[nt]);
        float e10 = __expf(v * 10.f);
        float e20 = e10 * e10;
        s1 += diag ? 1.f : e10;
        ps += (same && !diag) ? v : 0.f;
        s2 += same ? 0.f : e20;
        vm = same ? vm : fmaxf(vm, v);
        if (!dg) {  // B-side accumulation (consumed only off-diagonal)
          bs1[nt] += e10;
          bps[nt] += same ? v : 0.f;
          bs2[nt] += same ? 0.f : e20;
          bvm[nt] = same ? bvm[nt] : fmaxf(bvm[nt], v);
        }
      }
#pragma unroll
      for (int o = 1; o < 16; o <<= 1) {
        ps += __shfl_xor(ps, o, 64);
        s1 += __shfl_xor(s1, o, 64);
        s2 += __shfl_xor(s2, o, 64);
        vm = fmaxf(vm, __shfl_xor(vm, o, 64));
      }
      if ((t & 15) == 0)
        part[(size_t)(rowBase + rowL) * NB + bx] =
            make_float4(ps, s1, s2, 20.f * vm);
    }
  }

  if (!dg) {
#pragma unroll
    for (int nt = 0; nt < 4; ++nt) {
      float ps = bps[nt], s1 = bs1[nt], s2 = bs2[nt], vm = bvm[nt];
#pragma unroll
      for (int o = 16; o < 64; o <<= 1) {
        ps += __shfl_xor(ps, o, 64);
        s1 += __shfl_xor(s1, o, 64);
        s2 += __shfl_xor(s2, o, 64);
        vm = fmaxf(vm, __shfl_xor(vm, o, 64));
      }
      if ((t >> 4) == 0)
        part[(size_t)(colBase + nt * 16 + (t & 15)) * NB + by] =
            make_float4(ps, s1, s2, 20.f * vm);
    }
  }
}

// --- 3. merge partials per row (64 colblocks -> full-wave reduce) ----------
__global__ void k_merge(const float4* __restrict__ part,
                        float* __restrict__ psumRow,
                        float* __restrict__ logS1, float* __restrict__ Srow,
                        int N, int NB) {
  int lane = threadIdx.x & 63;
  int w = threadIdx.x >> 6;
  int row = blockIdx.x * 4 + w;
  float ps = 0.f, s1 = 0.f, s2 = 0.f, m2 = -1e30f;
  if (lane < NB) {
    float4 p = part[(size_t)row * NB + lane];
    ps = p.x; s1 = p.y; s2 = p.z; m2 = p.w;
  }
#pragma unroll
  for (int o = 32; o > 0; o >>= 1) {
    ps += __shfl_down(ps, o, 64);
    s1 += __shfl_down(s1, o, 64);
    s2 += __shfl_down(s2, o, 64);
    m2 = fmaxf(m2, __shfl_down(m2, o, 64));
  }
  if (lane == 0) {
    psumRow[row] = ps;
    logS1[row] = logf(s1);
    Srow[row] = (m2 < -1e29f) ? 0.f : s2 * expf(-m2);
  }
}

// --- 4. finalize ----------------------------------------------------------
__global__ void k_final(const float* __restrict__ ce_row,
                        const float* __restrict__ psumRow,
                        const float* __restrict__ logS1,
                        const float* __restrict__ Srow,
                        const int* __restrict__ lab, float* __restrict__ out,
                        int N, int C) {
  __shared__ float classS[32];
  __shared__ int classCnt[32];
  __shared__ float sbuf[8];
  if (threadIdx.x < 32) {
    classS[threadIdx.x] = 0.f;
    classCnt[threadIdx.x] = 0;
  }
  __syncthreads();
  float sumCe = 0.f;
  for (int i = threadIdx.x; i < N; i += blockDim.x) {
    sumCe += ce_row[i];
    int l = lab[i];
    atomicAdd(&classCnt[l], 1);
    atomicAdd(&classS[l], Srow[i]);
  }
  __syncthreads();
  float sumP1 = 0.f;
  for (int i = threadIdx.x; i < N; i += blockDim.x) {
    int l = lab[i];
    int pc = classCnt[l] - 1;
    if (pc > 0) sumP1 += psumRow[i] * 10.f / (float)pc - logS1[i];
  }
  sumCe = blockReduceSum(sumCe, sbuf);
  sumP1 = blockReduceSum(sumP1, sbuf);
  if (threadIdx.x == 0) {
    float totS = 0.f;
    for (int c = 0; c < C; ++c) totS += classS[c];
    float l2sum = 0.f;
    for (int c = 0; c < C; ++c) {
      int cnt = classCnt[c];
      if (cnt >= 2) {
        float negs = (float)(N - cnt);
        float x = (totS - classS[c]) / negs;
        l2sum += (float)cnt * logf(x + 1e-12f);
      }
    }
    float ce = sumCe / (float)N;
    float ntx1 = -sumP1 / (float)N;
    float ntx2 = l2sum / (float)N;
    out[0] = 0.5f * ce + 0.5f * ntx1 + 0.25f * ntx2;
  }
}

extern "C" void kernel_launch(void* const* d_in, const int* in_sizes, int n_in,
                              void* d_out, int out_size, void* d_ws,
                              size_t ws_size, hipStream_t stream) {
  const float* X = (const float*)d_in[0];  // cls_feats [N,D]
  const float* P = (const float*)d_in[1];  // predicts  [N,C]
  const int* tgt = (const int*)d_in[2];    // targets   [N]
  float* out = (float*)d_out;

  int N = in_sizes[2];
  int D = in_sizes[0] / N;
  int C = in_sizes[1] / N;
  int NB = N / 64;

  char* ws = (char*)d_ws;
  unsigned short* Ab = (unsigned short*)ws;          // N*D bf16
  float4* part = (float4*)(ws + (size_t)N * D * 2);  // N*NB float4
  float* ce_row = (float*)((char*)part + (size_t)N * NB * 16);
  float* psumRow = ce_row + N;
  float* logS1 = psumRow + N;
  float* Srow = logS1 + N;

  k_prep<<<N, 256, 0, stream>>>(X, P, tgt, Ab, ce_row, D, C);
  int nblk = NB * (NB + 1) / 2;
  k_gemm_fused<<<nblk, 64, 0, stream>>>(Ab, tgt, part, N, D, NB);
  k_merge<<<N / 4, 256, 0, stream>>>(part, psumRow, logS1, Srow, N, NB);
  k_final<<<1, 256, 0, stream>>>(ce_row, psumRow, logS1, Srow, tgt, out, N, C);
}